// Round 1
// baseline (19556.831 us; speedup 1.0000x reference)
//
#include <hip/hip_runtime.h>

#define N_NODES 200000
#define CDIM 128
#define NSCALE 6
#define NEP 100000
#define NEL 25000

enum { P_PLAIN = 0, P_TWO = 1, P_META = 2, P_GATHER = 3 };
enum { E_STORE = 0, E_GN = 1, E_RELU = 2, E_RES = 4, E_SCATTER = 8 };

__device__ __forceinline__ float4 ld4(const float* p) { return *(const float4*)p; }
__device__ __forceinline__ void st4(float* p, float4 v) { *(float4*)p = v; }

__device__ __forceinline__ void atomicAddF(float* p, float v) {
  __hip_atomic_fetch_add(p, v, __ATOMIC_RELAXED, __HIP_MEMORY_SCOPE_AGENT);
}

// Tiled GEMM: Y[M,128] = prologue(A)[M,K] @ W[K,128] (+ epilogue)
// Block: 256 threads, tile 64 rows x 128 cols, BK=16. Thread tile 4x8.
template<int PRO, int EPI>
__global__ __launch_bounds__(256)
void gemm_k(int M, int K,
            const float* __restrict__ A, const float* __restrict__ A2,
            const float* __restrict__ e0, const float* __restrict__ e1,
            const float* __restrict__ e2,
            const int* __restrict__ gidx, const int* __restrict__ sidx, int istride,
            const float* __restrict__ W, int wstride,
            float* __restrict__ Y,
            const float* __restrict__ gn_g, const float* __restrict__ gn_b,
            const float* __restrict__ R)
{
  __shared__ float As[16][68];   // [kk][m], padded stride 68 (16B-aligned rows, low write conflict)
  __shared__ float Bs[16][128];  // [kk][c]

  if (blockIdx.y) {
    W += (size_t)blockIdx.y * wstride;
    if (gidx) gidx += (size_t)blockIdx.y * istride;
    if (sidx) sidx += (size_t)blockIdx.y * istride;
  }

  const int tid = threadIdx.x;
  const int tx = tid & 15, ty = tid >> 4;
  const int rm = ty * 4;        // first of this thread's 4 rows (block-local)
  const int cn = tx * 8;        // first of this thread's 8 cols
  const int row0 = blockIdx.x * 64;

  float acc[4][8];
  #pragma unroll
  for (int i = 0; i < 4; i++)
    #pragma unroll
    for (int j = 0; j < 8; j++) acc[i][j] = 0.0f;

  const int am = tid >> 2;            // 0..63 : A-tile row this thread stages
  const int ak = (tid & 3) * 4;       // 0,4,8,12 : k-offset (float4)
  const int bk = tid >> 4;            // 0..15 : B-tile k-row this thread stages
  const int bc = (tid & 15) * 8;      // col offset (2x float4)

  const int nk = (K + 15) >> 4;
  for (int kt = 0; kt < nk; ++kt) {
    const int k0 = kt * 16;
    // ---- stage A tile (transposed into LDS) ----
    {
      float4 v = make_float4(0.f, 0.f, 0.f, 0.f);
      const int row = row0 + am;
      if (row < M) {
        if constexpr (PRO == P_PLAIN) {
          v = ld4(A + (size_t)row * 128 + k0 + ak);
        } else if constexpr (PRO == P_GATHER) {
          const int g = gidx[row];
          v = ld4(A + (size_t)g * 128 + k0 + ak);
        } else if constexpr (PRO == P_TWO) {
          const float x0 = A[(size_t)row * 2], x1 = A[(size_t)row * 2 + 1];
          const float4 wa = ld4(e0 + k0 + ak);
          const float4 wb = ld4(e0 + 128 + k0 + ak);
          const float4 bb = ld4(e1 + k0 + ak);
          v.x = fmaxf(0.f, fmaf(x0, wa.x, fmaf(x1, wb.x, bb.x)));
          v.y = fmaxf(0.f, fmaf(x0, wa.y, fmaf(x1, wb.y, bb.y)));
          v.z = fmaxf(0.f, fmaf(x0, wa.z, fmaf(x1, wb.z, bb.z)));
          v.w = fmaxf(0.f, fmaf(x0, wa.w, fmaf(x1, wb.w, bb.w)));
        } else { // P_META: cols [0,128)=relu(A+A2), 128,129=turn, 130=control, 131=intersect
          const int k = k0 + ak;
          if (k < 128) {
            const float4 va = ld4(A + (size_t)row * 128 + k);
            const float4 vb = ld4(A2 + (size_t)row * 128 + k);
            v.x = fmaxf(0.f, va.x + vb.x);
            v.y = fmaxf(0.f, va.y + vb.y);
            v.z = fmaxf(0.f, va.z + vb.z);
            v.w = fmaxf(0.f, va.w + vb.w);
          } else if (k == 128) {
            v = make_float4(e0[(size_t)row * 2], e0[(size_t)row * 2 + 1], e1[row], e2[row]);
          } // k >= 132: zeros
        }
      }
      As[ak + 0][am] = v.x;
      As[ak + 1][am] = v.y;
      As[ak + 2][am] = v.z;
      As[ak + 3][am] = v.w;
    }
    // ---- stage B tile ----
    {
      const int k = k0 + bk;
      float4 b0 = make_float4(0.f, 0.f, 0.f, 0.f), b1 = b0;
      if (k < K) {
        b0 = ld4(W + (size_t)k * 128 + bc);
        b1 = ld4(W + (size_t)k * 128 + bc + 4);
      }
      st4(&Bs[bk][bc], b0);
      st4(&Bs[bk][bc + 4], b1);
    }
    __syncthreads();
    // ---- compute ----
    #pragma unroll
    for (int kk = 0; kk < 16; ++kk) {
      const float4 af = *(const float4*)&As[kk][rm];
      const float4 bx = *(const float4*)&Bs[kk][cn];
      const float4 by = *(const float4*)&Bs[kk][cn + 4];
      const float a_[4] = {af.x, af.y, af.z, af.w};
      const float b_[8] = {bx.x, bx.y, bx.z, bx.w, by.x, by.y, by.z, by.w};
      #pragma unroll
      for (int i = 0; i < 4; i++)
        #pragma unroll
        for (int j = 0; j < 8; j++)
          acc[i][j] = fmaf(a_[i], b_[j], acc[i][j]);
    }
    __syncthreads();
  }

  // ---- epilogue ----
  if constexpr ((EPI & E_SCATTER) != 0) {
    #pragma unroll
    for (int i = 0; i < 4; i++) {
      const int r = row0 + rm + i;
      if (r < M) {
        const int d = sidx[r];
        float* p = Y + (size_t)d * 128 + cn;
        #pragma unroll
        for (int j = 0; j < 8; j++) atomicAddF(p + j, acc[i][j]);
      }
    }
  } else if constexpr ((EPI & E_GN) != 0) {
    __shared__ float2 red[64][16];
    __shared__ float2 stats[64];
    #pragma unroll
    for (int i = 0; i < 4; i++) {
      float s1 = 0.f, s2 = 0.f;
      #pragma unroll
      for (int j = 0; j < 8; j++) { s1 += acc[i][j]; s2 += acc[i][j] * acc[i][j]; }
      red[rm + i][tx] = make_float2(s1, s2);
    }
    __syncthreads();
    if (tid < 64) {
      float s1 = 0.f, s2 = 0.f;
      #pragma unroll
      for (int t = 0; t < 16; t++) { const float2 p = red[tid][t]; s1 += p.x; s2 += p.y; }
      const float mean = s1 * (1.0f / 128.0f);
      const float var = s2 * (1.0f / 128.0f) - mean * mean;
      stats[tid] = make_float2(mean, rsqrtf(var + 1e-5f));
    }
    __syncthreads();
    const float4 ga = ld4(gn_g + cn), gb = ld4(gn_g + cn + 4);
    const float4 ba = ld4(gn_b + cn), bb = ld4(gn_b + cn + 4);
    const float gg[8] = {ga.x, ga.y, ga.z, ga.w, gb.x, gb.y, gb.z, gb.w};
    const float bv[8] = {ba.x, ba.y, ba.z, ba.w, bb.x, bb.y, bb.z, bb.w};
    #pragma unroll
    for (int i = 0; i < 4; i++) {
      const int r = row0 + rm + i;
      if (r >= M) continue;
      const float2 st = stats[rm + i];
      float o[8];
      float rs[8];
      if constexpr ((EPI & E_RES) != 0) {
        const float4 r0 = ld4(R + (size_t)r * 128 + cn);
        const float4 r1 = ld4(R + (size_t)r * 128 + cn + 4);
        rs[0] = r0.x; rs[1] = r0.y; rs[2] = r0.z; rs[3] = r0.w;
        rs[4] = r1.x; rs[5] = r1.y; rs[6] = r1.z; rs[7] = r1.w;
      }
      #pragma unroll
      for (int j = 0; j < 8; j++) {
        float v = (acc[i][j] - st.x) * st.y * gg[j] + bv[j];
        if constexpr ((EPI & E_RES) != 0) v += rs[j];
        if constexpr ((EPI & E_RELU) != 0) v = fmaxf(v, 0.f);
        o[j] = v;
      }
      st4(Y + (size_t)r * 128 + cn, make_float4(o[0], o[1], o[2], o[3]));
      st4(Y + (size_t)r * 128 + cn + 4, make_float4(o[4], o[5], o[6], o[7]));
    }
  } else {
    #pragma unroll
    for (int i = 0; i < 4; i++) {
      const int r = row0 + rm + i;
      if (r < M) {
        st4(Y + (size_t)r * 128 + cn, make_float4(acc[i][0], acc[i][1], acc[i][2], acc[i][3]));
        st4(Y + (size_t)r * 128 + cn + 4, make_float4(acc[i][4], acc[i][5], acc[i][6], acc[i][7]));
      }
    }
  }
}

// In-place relu(groupnorm(row)) over T[M,128]; one wave per row.
__global__ __launch_bounds__(256)
void gn_relu_k(float* __restrict__ T, const float* __restrict__ g,
               const float* __restrict__ b, int M)
{
  const int lane = threadIdx.x & 63;
  const int wid = blockIdx.x * 4 + (threadIdx.x >> 6);
  const int nw = gridDim.x * 4;
  const float2 g2 = *(const float2*)(g + lane * 2);
  const float2 b2 = *(const float2*)(b + lane * 2);
  for (int row = wid; row < M; row += nw) {
    float2 v = *(float2*)(T + (size_t)row * 128 + lane * 2);
    float s1 = v.x + v.y, s2 = v.x * v.x + v.y * v.y;
    #pragma unroll
    for (int off = 32; off; off >>= 1) {
      s1 += __shfl_xor(s1, off, 64);
      s2 += __shfl_xor(s2, off, 64);
    }
    const float mean = s1 * (1.0f / 128.0f);
    const float rstd = rsqrtf(s2 * (1.0f / 128.0f) - mean * mean + 1e-5f);
    v.x = fmaxf(0.f, (v.x - mean) * rstd * g2.x + b2.x);
    v.y = fmaxf(0.f, (v.y - mean) * rstd * g2.y + b2.y);
    *(float2*)(T + (size_t)row * 128 + lane * 2) = v;
  }
}

__global__ __launch_bounds__(256)
void copy_k(const float* __restrict__ src, float* __restrict__ dst, int n)
{
  const int i = blockIdx.x * 256 + threadIdx.x;
  if (i < n) dst[i] = src[i];
}

extern "C" void kernel_launch(void* const* d_in, const int* in_sizes, int n_in,
                              void* d_out, int out_size, void* d_ws, size_t ws_size,
                              hipStream_t stream) {
  const float* control   = (const float*)d_in[0];
  const float* turn      = (const float*)d_in[1];
  const float* intersect = (const float*)d_in[2];
  const float* ctrs      = (const float*)d_in[3];
  const float* feats     = (const float*)d_in[4];
  const int*   pre   = (const int*)d_in[5];
  const int*   suc   = (const int*)d_in[6];
  const int*   left  = (const int*)d_in[7];
  const int*   right = (const int*)d_in[8];
  const float* w_in1   = (const float*)d_in[9];
  const float* b_in1   = (const float*)d_in[10];
  const float* w_in2   = (const float*)d_in[11];
  const float* gn_in_g = (const float*)d_in[12];
  const float* gn_in_b = (const float*)d_in[13];
  const float* w_seg1   = (const float*)d_in[14];
  const float* b_seg1   = (const float*)d_in[15];
  const float* w_seg2   = (const float*)d_in[16];
  const float* gn_seg_g = (const float*)d_in[17];
  const float* gn_seg_b = (const float*)d_in[18];
  const float* w_meta    = (const float*)d_in[19];
  const float* gn_meta_g = (const float*)d_in[20];
  const float* gn_meta_b = (const float*)d_in[21];
  const float* ctr_w   = (const float*)d_in[22];
  const float* pre_w   = (const float*)d_in[23];
  const float* suc_w   = (const float*)d_in[24];
  const float* left_w  = (const float*)d_in[25];
  const float* right_w = (const float*)d_in[26];
  const float* norm_g  = (const float*)d_in[27];
  const float* norm_b  = (const float*)d_in[28];
  const float* ctr2_w  = (const float*)d_in[29];
  const float* ctr2_g  = (const float*)d_in[30];
  const float* ctr2_b  = (const float*)d_in[31];

  float* F = (float*)d_ws;                      // feat / res (they coincide at layer start)
  float* T = F + (size_t)N_NODES * CDIM;        // temp
  float* out = (float*)d_out;

  const dim3 blk(256);
  const dim3 gN(N_NODES / 64);        // 3125
  const dim3 gEP((NEP + 63) / 64, NSCALE);
  const dim3 gEL((NEL + 63) / 64);

  // a-branch: T = GN(relu(ctrs@w_in1+b_in1) @ w_in2)
  gemm_k<P_TWO, E_GN><<<gN, blk, 0, stream>>>(N_NODES, 128, ctrs, nullptr, w_in1, b_in1, nullptr,
      nullptr, nullptr, 0, w_in2, 0, T, gn_in_g, gn_in_b, nullptr);
  // b-branch: F = GN(relu(feats@w_seg1+b_seg1) @ w_seg2)
  gemm_k<P_TWO, E_GN><<<gN, blk, 0, stream>>>(N_NODES, 128, feats, nullptr, w_seg1, b_seg1, nullptr,
      nullptr, nullptr, 0, w_seg2, 0, F, gn_seg_g, gn_seg_b, nullptr);
  // meta: F = relu(GN(concat(relu(T+F), turn, control, intersect) @ w_meta))   (in place, row-local)
  gemm_k<P_META, E_GN | E_RELU><<<gN, blk, 0, stream>>>(N_NODES, 132, T, F, turn, control, intersect,
      nullptr, nullptr, 0, w_meta, 0, F, gn_meta_g, gn_meta_b, nullptr);

  for (int i = 0; i < 4; i++) {
    // temp = feat @ ctr_w[i]  (writes every row; no memset needed)
    gemm_k<P_PLAIN, E_STORE><<<gN, blk, 0, stream>>>(N_NODES, 128, F, nullptr, nullptr, nullptr, nullptr,
        nullptr, nullptr, 0, ctr_w + (size_t)i * 16384, 0, T, nullptr, nullptr, nullptr);
    // pre: 6 scales, gather src -> GEMM -> atomic scatter-add to dst
    gemm_k<P_GATHER, E_SCATTER><<<gEP, blk, 0, stream>>>(NEP, 128, F, nullptr, nullptr, nullptr, nullptr,
        pre + NEP, pre, 2 * NEP, pre_w + (size_t)i * NSCALE * 16384, 16384, T, nullptr, nullptr, nullptr);
    // suc
    gemm_k<P_GATHER, E_SCATTER><<<gEP, blk, 0, stream>>>(NEP, 128, F, nullptr, nullptr, nullptr, nullptr,
        suc + NEP, suc, 2 * NEP, suc_w + (size_t)i * NSCALE * 16384, 16384, T, nullptr, nullptr, nullptr);
    // left
    gemm_k<P_GATHER, E_SCATTER><<<gEL, blk, 0, stream>>>(NEL, 128, F, nullptr, nullptr, nullptr, nullptr,
        left + NEL, left, 0, left_w + (size_t)i * 16384, 0, T, nullptr, nullptr, nullptr);
    // right
    gemm_k<P_GATHER, E_SCATTER><<<gEL, blk, 0, stream>>>(NEL, 128, F, nullptr, nullptr, nullptr, nullptr,
        right + NEL, right, 0, right_w + (size_t)i * 16384, 0, T, nullptr, nullptr, nullptr);
    // T = relu(GN(T))
    gn_relu_k<<<gN, blk, 0, stream>>>(T, norm_g + i * 128, norm_b + i * 128, N_NODES);
    // feat = relu(GN(T @ ctr2_w[i]) + res); res==feat at layer start, so R=F, Y=F (in place, element-local)
    gemm_k<P_PLAIN, E_GN | E_RES | E_RELU><<<gN, blk, 0, stream>>>(N_NODES, 128, T, nullptr, nullptr, nullptr,
        nullptr, nullptr, nullptr, 0, ctr2_w + (size_t)i * 16384, 0,
        (i == 3) ? out : F, ctr2_g + i * 128, ctr2_b + i * 128, F);
  }

  // out tail: ctrs passthrough
  copy_k<<<dim3((2 * N_NODES + 255) / 256), blk, 0, stream>>>(ctrs, out + (size_t)N_NODES * CDIM, 2 * N_NODES);
}

// Round 2
// 6451.557 us; speedup vs baseline: 3.0313x; 3.0313x over previous
//
#include <hip/hip_runtime.h>

#define N_NODES 200000
#define CDIM 128
#define NSCALE 6
#define NEP 100000
#define NEL 25000
#define NCLS 14

enum { P_PLAIN = 0, P_TWO = 1, P_META = 2, P_GATHER = 3 };
enum { E_STORE = 0, E_GN = 1, E_RELU = 2, E_RES = 4 };

__device__ __forceinline__ float4 ld4(const float* p) { return *(const float4*)p; }
__device__ __forceinline__ void st4(float* p, float4 v) { *(float4*)p = v; }

// Tiled GEMM: Y[M,128] = prologue(A)[M,K] @ W[K,128] (+ epilogue)
// Block: 256 threads, tile 64 rows x 128 cols, BK=16. Thread tile 4x8.
template<int PRO, int EPI>
__global__ __launch_bounds__(256)
void gemm_k(int M, int K,
            const float* __restrict__ A, const float* __restrict__ A2,
            const float* __restrict__ e0, const float* __restrict__ e1,
            const float* __restrict__ e2,
            const int* __restrict__ gidx,
            const float* __restrict__ W,
            float* __restrict__ Y,
            const float* __restrict__ gn_g, const float* __restrict__ gn_b,
            const float* __restrict__ R)
{
  __shared__ float As[16][68];   // [kk][m], padded
  __shared__ float Bs[16][128];  // [kk][c]

  const int tid = threadIdx.x;
  const int tx = tid & 15, ty = tid >> 4;
  const int rm = ty * 4;
  const int cn = tx * 8;
  const int row0 = blockIdx.x * 64;

  float acc[4][8];
  #pragma unroll
  for (int i = 0; i < 4; i++)
    #pragma unroll
    for (int j = 0; j < 8; j++) acc[i][j] = 0.0f;

  const int am = tid >> 2;
  const int ak = (tid & 3) * 4;
  const int bk = tid >> 4;
  const int bc = (tid & 15) * 8;

  const int nk = (K + 15) >> 4;
  for (int kt = 0; kt < nk; ++kt) {
    const int k0 = kt * 16;
    {
      float4 v = make_float4(0.f, 0.f, 0.f, 0.f);
      const int row = row0 + am;
      if (row < M) {
        if constexpr (PRO == P_PLAIN) {
          v = ld4(A + (size_t)row * 128 + k0 + ak);
        } else if constexpr (PRO == P_GATHER) {
          const int g = gidx[row];
          v = ld4(A + (size_t)g * 128 + k0 + ak);
        } else if constexpr (PRO == P_TWO) {
          const float x0 = A[(size_t)row * 2], x1 = A[(size_t)row * 2 + 1];
          const float4 wa = ld4(e0 + k0 + ak);
          const float4 wb = ld4(e0 + 128 + k0 + ak);
          const float4 bb = ld4(e1 + k0 + ak);
          v.x = fmaxf(0.f, fmaf(x0, wa.x, fmaf(x1, wb.x, bb.x)));
          v.y = fmaxf(0.f, fmaf(x0, wa.y, fmaf(x1, wb.y, bb.y)));
          v.z = fmaxf(0.f, fmaf(x0, wa.z, fmaf(x1, wb.z, bb.z)));
          v.w = fmaxf(0.f, fmaf(x0, wa.w, fmaf(x1, wb.w, bb.w)));
        } else { // P_META
          const int k = k0 + ak;
          if (k < 128) {
            const float4 va = ld4(A + (size_t)row * 128 + k);
            const float4 vb = ld4(A2 + (size_t)row * 128 + k);
            v.x = fmaxf(0.f, va.x + vb.x);
            v.y = fmaxf(0.f, va.y + vb.y);
            v.z = fmaxf(0.f, va.z + vb.z);
            v.w = fmaxf(0.f, va.w + vb.w);
          } else if (k == 128) {
            v = make_float4(e0[(size_t)row * 2], e0[(size_t)row * 2 + 1], e1[row], e2[row]);
          }
        }
      }
      As[ak + 0][am] = v.x;
      As[ak + 1][am] = v.y;
      As[ak + 2][am] = v.z;
      As[ak + 3][am] = v.w;
    }
    {
      const int k = k0 + bk;
      float4 b0 = make_float4(0.f, 0.f, 0.f, 0.f), b1 = b0;
      if (k < K) {
        b0 = ld4(W + (size_t)k * 128 + bc);
        b1 = ld4(W + (size_t)k * 128 + bc + 4);
      }
      st4(&Bs[bk][bc], b0);
      st4(&Bs[bk][bc + 4], b1);
    }
    __syncthreads();
    #pragma unroll
    for (int kk = 0; kk < 16; ++kk) {
      const float4 af = *(const float4*)&As[kk][rm];
      const float4 bx = *(const float4*)&Bs[kk][cn];
      const float4 by = *(const float4*)&Bs[kk][cn + 4];
      const float a_[4] = {af.x, af.y, af.z, af.w};
      const float b_[8] = {bx.x, bx.y, bx.z, bx.w, by.x, by.y, by.z, by.w};
      #pragma unroll
      for (int i = 0; i < 4; i++)
        #pragma unroll
        for (int j = 0; j < 8; j++)
          acc[i][j] = fmaf(a_[i], b_[j], acc[i][j]);
    }
    __syncthreads();
  }

  if constexpr ((EPI & E_GN) != 0) {
    __shared__ float2 red[64][16];
    __shared__ float2 stats[64];
    #pragma unroll
    for (int i = 0; i < 4; i++) {
      float s1 = 0.f, s2 = 0.f;
      #pragma unroll
      for (int j = 0; j < 8; j++) { s1 += acc[i][j]; s2 += acc[i][j] * acc[i][j]; }
      red[rm + i][tx] = make_float2(s1, s2);
    }
    __syncthreads();
    if (tid < 64) {
      float s1 = 0.f, s2 = 0.f;
      #pragma unroll
      for (int t = 0; t < 16; t++) { const float2 p = red[tid][t]; s1 += p.x; s2 += p.y; }
      const float mean = s1 * (1.0f / 128.0f);
      const float var = s2 * (1.0f / 128.0f) - mean * mean;
      stats[tid] = make_float2(mean, rsqrtf(var + 1e-5f));
    }
    __syncthreads();
    const float4 ga = ld4(gn_g + cn), gb = ld4(gn_g + cn + 4);
    const float4 ba = ld4(gn_b + cn), bb = ld4(gn_b + cn + 4);
    const float gg[8] = {ga.x, ga.y, ga.z, ga.w, gb.x, gb.y, gb.z, gb.w};
    const float bv[8] = {ba.x, ba.y, ba.z, ba.w, bb.x, bb.y, bb.z, bb.w};
    #pragma unroll
    for (int i = 0; i < 4; i++) {
      const int r = row0 + rm + i;
      if (r >= M) continue;
      const float2 st = stats[rm + i];
      float o[8];
      float rs[8];
      if constexpr ((EPI & E_RES) != 0) {
        const float4 r0 = ld4(R + (size_t)r * 128 + cn);
        const float4 r1 = ld4(R + (size_t)r * 128 + cn + 4);
        rs[0] = r0.x; rs[1] = r0.y; rs[2] = r0.z; rs[3] = r0.w;
        rs[4] = r1.x; rs[5] = r1.y; rs[6] = r1.z; rs[7] = r1.w;
      }
      #pragma unroll
      for (int j = 0; j < 8; j++) {
        float v = (acc[i][j] - st.x) * st.y * gg[j] + bv[j];
        if constexpr ((EPI & E_RES) != 0) v += rs[j];
        if constexpr ((EPI & E_RELU) != 0) v = fmaxf(v, 0.f);
        o[j] = v;
      }
      st4(Y + (size_t)r * 128 + cn, make_float4(o[0], o[1], o[2], o[3]));
      st4(Y + (size_t)r * 128 + cn + 4, make_float4(o[4], o[5], o[6], o[7]));
    }
  } else {
    #pragma unroll
    for (int i = 0; i < 4; i++) {
      const int r = row0 + rm + i;
      if (r < M) {
        st4(Y + (size_t)r * 128 + cn, make_float4(acc[i][0], acc[i][1], acc[i][2], acc[i][3]));
        st4(Y + (size_t)r * 128 + cn + 4, make_float4(acc[i][4], acc[i][5], acc[i][6], acc[i][7]));
      }
    }
  }
}

// ---------------- CSR build ----------------
struct EdgeCfg { const int* dst[NCLS]; int cnt[NCLS]; };

__global__ __launch_bounds__(256)
void hist_k(EdgeCfg cfg, int* __restrict__ ptrs)
{
  const int c = blockIdx.y;
  const int i = blockIdx.x * 256 + threadIdx.x;
  if (i < cfg.cnt[c]) atomicAdd(ptrs + (size_t)c * (N_NODES + 1) + cfg.dst[c][i], 1);
}

__global__ __launch_bounds__(1024)
void scan_k(int* __restrict__ ptrs)
{
  const int c = blockIdx.x;
  int* deg = ptrs + (size_t)c * (N_NODES + 1);
  __shared__ int part[1024];
  const int n = N_NODES;
  const int chunk = (n + 1023) / 1024;
  const int lo = threadIdx.x * chunk;
  const int hi = min(lo + chunk, n);
  int s = 0;
  for (int i = lo; i < hi; i++) s += deg[i];
  part[threadIdx.x] = s;
  __syncthreads();
  if (threadIdx.x == 0) {
    int run = 0;
    for (int i = 0; i < 1024; i++) { int t = part[i]; part[i] = run; run += t; }
  }
  __syncthreads();
  int base = part[threadIdx.x];
  for (int i = lo; i < hi; i++) { int d = deg[i]; deg[i] = base; base += d; }
  if (hi == n && lo < n) deg[n] = base;
}

__device__ __forceinline__ int idx_base(int c) {
  return (c < 12) ? c * NEP : 12 * NEP + (c - 12) * NEL;
}

// fill uses ptrs as cursors: after fill, ptrs[c][d] == end offset of dst d.
__global__ __launch_bounds__(256)
void fill_k(EdgeCfg cfg, int* __restrict__ ptrs, int* __restrict__ idxs)
{
  const int c = blockIdx.y;
  const int i = blockIdx.x * 256 + threadIdx.x;
  if (i >= cfg.cnt[c]) return;
  const int d = cfg.dst[c][i];
  const int slot = atomicAdd(ptrs + (size_t)c * (N_NODES + 1) + d, 1);
  idxs[idx_base(c) + slot] = i;
}

// T[d] += sum of Msg rows for dst d (CSR with end-offsets)
__global__ __launch_bounds__(256)
void gather_k(const int* __restrict__ end, const int* __restrict__ idx,
              const float* __restrict__ Msg, float* __restrict__ T)
{
  const int lane = threadIdx.x & 63;
  const int nw = gridDim.x * 4;
  for (int d = blockIdx.x * 4 + (threadIdx.x >> 6); d < N_NODES; d += nw) {
    const int hi = end[d];
    const int lo = d ? end[d - 1] : 0;
    if (lo == hi) continue;
    float2 acc = make_float2(0.f, 0.f);
    for (int p = lo; p < hi; ++p) {
      const float2 m = *(const float2*)(Msg + (size_t)idx[p] * CDIM + lane * 2);
      acc.x += m.x; acc.y += m.y;
    }
    float2* tp = (float2*)(T + (size_t)d * CDIM + lane * 2);
    float2 t = *tp; t.x += acc.x; t.y += acc.y; *tp = t;
  }
}

__global__ __launch_bounds__(256)
void gn_relu_k(float* __restrict__ T, const float* __restrict__ g,
               const float* __restrict__ b, int M)
{
  const int lane = threadIdx.x & 63;
  const int wid = blockIdx.x * 4 + (threadIdx.x >> 6);
  const int nw = gridDim.x * 4;
  const float2 g2 = *(const float2*)(g + lane * 2);
  const float2 b2 = *(const float2*)(b + lane * 2);
  for (int row = wid; row < M; row += nw) {
    float2 v = *(float2*)(T + (size_t)row * 128 + lane * 2);
    float s1 = v.x + v.y, s2 = v.x * v.x + v.y * v.y;
    #pragma unroll
    for (int off = 32; off; off >>= 1) {
      s1 += __shfl_xor(s1, off, 64);
      s2 += __shfl_xor(s2, off, 64);
    }
    const float mean = s1 * (1.0f / 128.0f);
    const float rstd = rsqrtf(s2 * (1.0f / 128.0f) - mean * mean + 1e-5f);
    v.x = fmaxf(0.f, (v.x - mean) * rstd * g2.x + b2.x);
    v.y = fmaxf(0.f, (v.y - mean) * rstd * g2.y + b2.y);
    *(float2*)(T + (size_t)row * 128 + lane * 2) = v;
  }
}

__global__ __launch_bounds__(256)
void copy_k(const float* __restrict__ src, float* __restrict__ dst, int n)
{
  const int i = blockIdx.x * 256 + threadIdx.x;
  if (i < n) dst[i] = src[i];
}

extern "C" void kernel_launch(void* const* d_in, const int* in_sizes, int n_in,
                              void* d_out, int out_size, void* d_ws, size_t ws_size,
                              hipStream_t stream) {
  const float* control   = (const float*)d_in[0];
  const float* turn      = (const float*)d_in[1];
  const float* intersect = (const float*)d_in[2];
  const float* ctrs      = (const float*)d_in[3];
  const float* feats     = (const float*)d_in[4];
  const int*   pre   = (const int*)d_in[5];
  const int*   suc   = (const int*)d_in[6];
  const int*   left  = (const int*)d_in[7];
  const int*   right = (const int*)d_in[8];
  const float* w_in1   = (const float*)d_in[9];
  const float* b_in1   = (const float*)d_in[10];
  const float* w_in2   = (const float*)d_in[11];
  const float* gn_in_g = (const float*)d_in[12];
  const float* gn_in_b = (const float*)d_in[13];
  const float* w_seg1   = (const float*)d_in[14];
  const float* b_seg1   = (const float*)d_in[15];
  const float* w_seg2   = (const float*)d_in[16];
  const float* gn_seg_g = (const float*)d_in[17];
  const float* gn_seg_b = (const float*)d_in[18];
  const float* w_meta    = (const float*)d_in[19];
  const float* gn_meta_g = (const float*)d_in[20];
  const float* gn_meta_b = (const float*)d_in[21];
  const float* ctr_w   = (const float*)d_in[22];
  const float* pre_w   = (const float*)d_in[23];
  const float* suc_w   = (const float*)d_in[24];
  const float* left_w  = (const float*)d_in[25];
  const float* right_w = (const float*)d_in[26];
  const float* norm_g  = (const float*)d_in[27];
  const float* norm_b  = (const float*)d_in[28];
  const float* ctr2_w  = (const float*)d_in[29];
  const float* ctr2_g  = (const float*)d_in[30];
  const float* ctr2_b  = (const float*)d_in[31];

  // workspace layout
  float* F     = (float*)d_ws;                              // [N,128]
  float* T     = F + (size_t)N_NODES * CDIM;                // [N,128]
  float* Arena = T + (size_t)N_NODES * CDIM;                // [NEP,128] msg arena (reused per class)
  int*   ptrs  = (int*)(Arena + (size_t)NEP * CDIM);        // [14][N+1]
  int*   idxs  = ptrs + (size_t)NCLS * (N_NODES + 1);       // [12*NEP + 2*NEL]
  float* out = (float*)d_out;

  // edge-class table: dst pointers for CSR, src pointers for gather-GEMM
  EdgeCfg cfg;
  const int* srcp[NCLS];
  for (int s = 0; s < NSCALE; s++) {
    cfg.dst[s] = pre + (size_t)s * 2 * NEP;       cfg.cnt[s] = NEP;
    srcp[s]    = pre + ((size_t)s * 2 + 1) * NEP;
    cfg.dst[6 + s] = suc + (size_t)s * 2 * NEP;   cfg.cnt[6 + s] = NEP;
    srcp[6 + s]    = suc + ((size_t)s * 2 + 1) * NEP;
  }
  cfg.dst[12] = left;  cfg.cnt[12] = NEL; srcp[12] = left + NEL;
  cfg.dst[13] = right; cfg.cnt[13] = NEL; srcp[13] = right + NEL;

  const dim3 blk(256);
  const dim3 gN(N_NODES / 64);                  // 3125
  const dim3 gEP((NEP + 63) / 64);              // 1563
  const dim3 gEL((NEL + 63) / 64);
  const dim3 gHist((NEP + 255) / 256, NCLS);

  // ---- CSR build (per call; edges static) ----
  hipMemsetAsync(ptrs, 0, (size_t)NCLS * (N_NODES + 1) * sizeof(int), stream);
  hist_k<<<gHist, blk, 0, stream>>>(cfg, ptrs);
  scan_k<<<dim3(NCLS), dim3(1024), 0, stream>>>(ptrs);
  fill_k<<<gHist, blk, 0, stream>>>(cfg, ptrs, idxs);

  // ---- prologue ----
  gemm_k<P_TWO, E_GN><<<gN, blk, 0, stream>>>(N_NODES, 128, ctrs, nullptr, w_in1, b_in1, nullptr,
      nullptr, w_in2, T, gn_in_g, gn_in_b, nullptr);
  gemm_k<P_TWO, E_GN><<<gN, blk, 0, stream>>>(N_NODES, 128, feats, nullptr, w_seg1, b_seg1, nullptr,
      nullptr, w_seg2, F, gn_seg_g, gn_seg_b, nullptr);
  gemm_k<P_META, E_GN | E_RELU><<<gN, blk, 0, stream>>>(N_NODES, 132, T, F, turn, control, intersect,
      nullptr, w_meta, F, gn_meta_g, gn_meta_b, nullptr);

  for (int i = 0; i < 4; i++) {
    // temp = feat @ ctr_w[i]
    gemm_k<P_PLAIN, E_STORE><<<gN, blk, 0, stream>>>(N_NODES, 128, F, nullptr, nullptr, nullptr, nullptr,
        nullptr, ctr_w + (size_t)i * 16384, T, nullptr, nullptr, nullptr);
    // 14 edge classes: msg GEMM into arena (plain stores), then CSR gather-reduce into T
    for (int c = 0; c < NCLS; c++) {
      const float* W =
          (c < 6)  ? pre_w  + ((size_t)i * NSCALE + c) * 16384 :
          (c < 12) ? suc_w  + ((size_t)i * NSCALE + (c - 6)) * 16384 :
          (c == 12) ? left_w + (size_t)i * 16384 :
                      right_w + (size_t)i * 16384;
      const int cnt = cfg.cnt[c];
      gemm_k<P_GATHER, E_STORE><<<(c < 12) ? gEP : gEL, blk, 0, stream>>>(cnt, 128, F, nullptr,
          nullptr, nullptr, nullptr, srcp[c], W, Arena, nullptr, nullptr, nullptr);
      gather_k<<<gN, blk, 0, stream>>>(ptrs + (size_t)c * (N_NODES + 1),
          idxs + ((c < 12) ? c * NEP : 12 * NEP + (c - 12) * NEL), Arena, T);
    }
    // T = relu(GN(T))
    gn_relu_k<<<gN, blk, 0, stream>>>(T, norm_g + i * 128, norm_b + i * 128, N_NODES);
    // feat = relu(GN(T @ ctr2_w[i]) + res)
    gemm_k<P_PLAIN, E_GN | E_RES | E_RELU><<<gN, blk, 0, stream>>>(N_NODES, 128, T, nullptr, nullptr, nullptr,
        nullptr, nullptr, ctr2_w + (size_t)i * 16384,
        (i == 3) ? out : F, ctr2_g + i * 128, ctr2_b + i * 128, F);
  }

  copy_k<<<dim3((2 * N_NODES + 255) / 256), blk, 0, stream>>>(ctrs, out + (size_t)N_NODES * CDIM, 2 * N_NODES);
}

// Round 4
// 4312.572 us; speedup vs baseline: 4.5348x; 1.4960x over previous
//
#include <hip/hip_runtime.h>

#define N_NODES 200000
#define CDIM 128
#define NSCALE 6
#define NEP 100000
#define NEL 25000
#define NCLS 14
#define NCHUNK 196   // ceil(200000/1024)

typedef unsigned short u16;
typedef unsigned int u32;

using fragAB = __attribute__((ext_vector_type(8))) short;  // 8 bf16
using fragC  = __attribute__((ext_vector_type(4))) float;  // 4 fp32

enum { P_PLAIN = 0, P_TWO = 1, P_META = 2, P_GATHER = 3, P_CVT32 = 4 };
enum { E_STORE = 0, E_GN = 1, E_RELU = 2, E_RES = 4, E_BF16 = 8 };

__device__ __forceinline__ float4 ld4(const float* p) { return *(const float4*)p; }

__device__ __forceinline__ u16 f2bf(float f) {
  u32 u = __builtin_bit_cast(u32, f);
  u = (u + 0x7fff + ((u >> 16) & 1)) >> 16;
  return (u16)u;
}
__device__ __forceinline__ u32 pk2(float a, float b) {
  return (u32)f2bf(a) | ((u32)f2bf(b) << 16);
}
__device__ __forceinline__ float bflo(u32 u) { return __builtin_bit_cast(float, u << 16); }
__device__ __forceinline__ float bfhi(u32 u) { return __builtin_bit_cast(float, u & 0xffff0000u); }

// ============ MFMA GEMM: Y[M,128] = prologue(A)[M,K] @ Wt^T, fused epilogue ============
// Block 256 thr = 4 waves (2x2), tile 128x128, BK=32. Wt is bf16 TRANSPOSED [128][Kp].
template<int PRO, int EPI>
__global__ __launch_bounds__(256)
void mm_k(int M, int K, int Kp,
          const float* __restrict__ Af, const u16* __restrict__ Ab,
          const float* __restrict__ A2f,
          const float* __restrict__ e0, const float* __restrict__ e1, const float* __restrict__ e2,
          const int* __restrict__ gidx,
          const u16* __restrict__ Wt,
          float* __restrict__ Y, u16* __restrict__ Yb,
          const float* __restrict__ gn_g, const float* __restrict__ gn_b,
          const float* __restrict__ R)
{
  constexpr int LSTR = 56;  // ushorts per LDS row: 32 data + 24 pad (112B, 16B-aligned, 2-way banks)
  __shared__ u16 As[128 * LSTR];
  __shared__ u16 Bs[128 * LSTR];

  const int tid = threadIdx.x;
  const int lane = tid & 63, wid = tid >> 6;
  const int wm = (wid >> 1) * 64, wn = (wid & 1) * 64;
  const int q = lane >> 4, l16 = lane & 15;
  const int row0 = blockIdx.x * 128;

  const int srow = tid >> 1;   // staging row 0..127
  const int shalf = tid & 1;   // k-offset 0/16 within BK

  fragC acc[4][4];
  #pragma unroll
  for (int i = 0; i < 4; i++)
    #pragma unroll
    for (int j = 0; j < 4; j++)
      #pragma unroll
      for (int e = 0; e < 4; e++) acc[i][j][e] = 0.0f;

  // hoisted per-row staging state
  const int sgrow = row0 + srow;
  const bool svalid = (sgrow < M);
  int gval = 0;
  float x0 = 0.f, x1 = 0.f;
  float mx = 0.f, my = 0.f, mc = 0.f, mi = 0.f;
  if constexpr (PRO == P_GATHER) { if (svalid) gval = gidx[sgrow]; }
  if constexpr (PRO == P_TWO) {
    if (svalid) { x0 = Af[(size_t)sgrow * 2]; x1 = Af[(size_t)sgrow * 2 + 1]; }
  }
  if constexpr (PRO == P_META) {
    if (svalid) { mx = e0[(size_t)sgrow * 2]; my = e0[(size_t)sgrow * 2 + 1]; mc = e1[sgrow]; mi = e2[sgrow]; }
  }

  const int nk = Kp >> 5;
  for (int kt = 0; kt < nk; ++kt) {
    const int k0 = kt * 32 + shalf * 16;
    // ---- stage A (16 bf16 for row srow) ----
    {
      u16* adst = &As[srow * LSTR + shalf * 16];
      if constexpr (PRO == P_PLAIN || PRO == P_GATHER) {
        uint4 lo = make_uint4(0, 0, 0, 0), hi = lo;
        if (svalid) {
          const int r = (PRO == P_GATHER) ? gval : sgrow;
          const u16* s = Ab + (size_t)r * 128 + k0;
          lo = *(const uint4*)s; hi = *(const uint4*)(s + 8);
        }
        *(uint4*)adst = lo; *(uint4*)(adst + 8) = hi;
      } else {
        float v[16];
        #pragma unroll
        for (int j = 0; j < 16; j++) v[j] = 0.f;
        if constexpr (PRO == P_CVT32) {
          if (svalid) {
            const float* s = Af + (size_t)sgrow * 128 + k0;
            #pragma unroll
            for (int j0 = 0; j0 < 16; j0 += 4) {
              float4 a = ld4(s + j0);
              v[j0] = a.x; v[j0 + 1] = a.y; v[j0 + 2] = a.z; v[j0 + 3] = a.w;
            }
          }
        } else if constexpr (PRO == P_TWO) {
          #pragma unroll
          for (int j0 = 0; j0 < 16; j0 += 4) {
            float4 wa = ld4(e0 + k0 + j0);
            float4 wb = ld4(e0 + 128 + k0 + j0);
            float4 bb = ld4(e1 + k0 + j0);
            v[j0]     = fmaxf(0.f, fmaf(x0, wa.x, fmaf(x1, wb.x, bb.x)));
            v[j0 + 1] = fmaxf(0.f, fmaf(x0, wa.y, fmaf(x1, wb.y, bb.y)));
            v[j0 + 2] = fmaxf(0.f, fmaf(x0, wa.z, fmaf(x1, wb.z, bb.z)));
            v[j0 + 3] = fmaxf(0.f, fmaf(x0, wa.w, fmaf(x1, wb.w, bb.w)));
          }
        } else { // P_META
          if (svalid) {
            if (k0 < 128) {
              const float* sa = Af + (size_t)sgrow * 128 + k0;
              const float* sb = A2f + (size_t)sgrow * 128 + k0;
              #pragma unroll
              for (int j0 = 0; j0 < 16; j0 += 4) {
                float4 a = ld4(sa + j0), b = ld4(sb + j0);
                v[j0]     = fmaxf(0.f, a.x + b.x);
                v[j0 + 1] = fmaxf(0.f, a.y + b.y);
                v[j0 + 2] = fmaxf(0.f, a.z + b.z);
                v[j0 + 3] = fmaxf(0.f, a.w + b.w);
              }
            } else {
              #pragma unroll
              for (int j = 0; j < 16; j++) {
                const int kk = k0 + j - 128;
                v[j] = (kk == 0) ? mx : (kk == 1) ? my : (kk == 2) ? mc : (kk == 3) ? mi : 0.f;
              }
            }
          }
        }
        u32 p[8];
        #pragma unroll
        for (int j = 0; j < 8; j++) p[j] = pk2(v[2 * j], v[2 * j + 1]);
        *(uint4*)adst = make_uint4(p[0], p[1], p[2], p[3]);
        *(uint4*)(adst + 8) = make_uint4(p[4], p[5], p[6], p[7]);
      }
    }
    // ---- stage B ----
    {
      const u16* s = Wt + (size_t)srow * Kp + k0;
      uint4 lo = *(const uint4*)s, hi = *(const uint4*)(s + 8);
      u16* bdst = &Bs[srow * LSTR + shalf * 16];
      *(uint4*)bdst = lo; *(uint4*)(bdst + 8) = hi;
    }
    __syncthreads();
    // ---- compute ----
    fragAB af[4], bf[4];
    #pragma unroll
    for (int t = 0; t < 4; t++) af[t] = *(const fragAB*)&As[(wm + t * 16 + l16) * LSTR + q * 8];
    #pragma unroll
    for (int t = 0; t < 4; t++) bf[t] = *(const fragAB*)&Bs[(wn + t * 16 + l16) * LSTR + q * 8];
    #pragma unroll
    for (int mt = 0; mt < 4; mt++)
      #pragma unroll
      for (int nt = 0; nt < 4; nt++)
        acc[mt][nt] = __builtin_amdgcn_mfma_f32_16x16x32_bf16(af[mt], bf[nt], acc[mt][nt], 0, 0, 0);
    __syncthreads();
  }

  // ---- epilogue ----
  // D layout per 16x16 tile: col = l16, row = q*4 + reg
  if constexpr ((EPI & E_GN) != 0) {
    __shared__ float2 red[128][2];
    __shared__ float2 stats[128];
    #pragma unroll
    for (int mt = 0; mt < 4; mt++)
      #pragma unroll
      for (int r = 0; r < 4; r++) {
        float s1 = acc[mt][0][r] + acc[mt][1][r] + acc[mt][2][r] + acc[mt][3][r];
        float s2 = acc[mt][0][r] * acc[mt][0][r] + acc[mt][1][r] * acc[mt][1][r]
                 + acc[mt][2][r] * acc[mt][2][r] + acc[mt][3][r] * acc[mt][3][r];
        #pragma unroll
        for (int off = 1; off < 16; off <<= 1) {
          s1 += __shfl_xor(s1, off, 64);
          s2 += __shfl_xor(s2, off, 64);
        }
        if (l16 == 0) red[wm + mt * 16 + q * 4 + r][wid & 1] = make_float2(s1, s2);
      }
    __syncthreads();
    if (tid < 128) {
      const float2 p0 = red[tid][0], p1 = red[tid][1];
      const float m = (p0.x + p1.x) * (1.0f / 128.0f);
      const float var = (p0.y + p1.y) * (1.0f / 128.0f) - m * m;
      stats[tid] = make_float2(m, rsqrtf(var + 1e-5f));
    }
    __syncthreads();
    float gl[4], bl[4];
    #pragma unroll
    for (int nt = 0; nt < 4; nt++) {
      gl[nt] = gn_g[wn + nt * 16 + l16];
      bl[nt] = gn_b[wn + nt * 16 + l16];
    }
    #pragma unroll
    for (int mt = 0; mt < 4; mt++)
      #pragma unroll
      for (int r = 0; r < 4; r++) {
        const int rl = wm + mt * 16 + q * 4 + r;
        const int grow = row0 + rl;
        if (grow >= M) continue;
        const float2 st = stats[rl];
        #pragma unroll
        for (int nt = 0; nt < 4; nt++) {
          const int col = wn + nt * 16 + l16;
          float v = (acc[mt][nt][r] - st.x) * st.y * gl[nt] + bl[nt];
          if constexpr ((EPI & E_RES) != 0) v += R[(size_t)grow * 128 + col];
          if constexpr ((EPI & E_RELU) != 0) v = fmaxf(v, 0.f);
          Y[(size_t)grow * 128 + col] = v;
          if (Yb) Yb[(size_t)grow * 128 + col] = f2bf(v);
        }
      }
  } else if constexpr ((EPI & E_BF16) != 0) {
    #pragma unroll
    for (int mt = 0; mt < 4; mt++)
      #pragma unroll
      for (int r = 0; r < 4; r++) {
        const int grow = row0 + wm + mt * 16 + q * 4 + r;
        if (grow >= M) continue;
        #pragma unroll
        for (int nt = 0; nt < 4; nt++)
          Yb[(size_t)grow * 128 + wn + nt * 16 + l16] = f2bf(acc[mt][nt][r]);
      }
  } else {
    #pragma unroll
    for (int mt = 0; mt < 4; mt++)
      #pragma unroll
      for (int r = 0; r < 4; r++) {
        const int grow = row0 + wm + mt * 16 + q * 4 + r;
        if (grow >= M) continue;
        #pragma unroll
        for (int nt = 0; nt < 4; nt++)
          Y[(size_t)grow * 128 + wn + nt * 16 + l16] = acc[mt][nt][r];
      }
  }
}

// ============ weight prep: fp32 [K,128] -> bf16 transposed [128,Kp] (zero-padded) ============
__global__ __launch_bounds__(256)
void prep_k(const float* __restrict__ in2, const float* __restrict__ seg2,
            const float* __restrict__ ctr, const float* __restrict__ ctr2,
            const float* __restrict__ lw, const float* __restrict__ rw,
            const float* __restrict__ pw, const float* __restrict__ sw,
            const float* __restrict__ meta, u16* __restrict__ Wt)
{
  const int id = blockIdx.x;
  const float* src;
  int K = 128, Kp = 128;
  if (id == 0) src = in2;
  else if (id == 1) src = seg2;
  else if (id < 6)  src = ctr  + (size_t)(id - 2) * 16384;
  else if (id < 10) src = ctr2 + (size_t)(id - 6) * 16384;
  else if (id < 14) src = lw   + (size_t)(id - 10) * 16384;
  else if (id < 18) src = rw   + (size_t)(id - 14) * 16384;
  else if (id < 42) src = pw   + (size_t)(id - 18) * 16384;
  else if (id < 66) src = sw   + (size_t)(id - 42) * 16384;
  else { src = meta; K = 132; Kp = 160; }
  u16* dst = Wt + (size_t)id * 16384;  // meta (id=66) sits at end, needs 128*160
  const int tot = 128 * Kp;
  for (int e = threadIdx.x; e < tot; e += 256) {
    const int n = e & 127, k = e >> 7;
    const float v = (k < K) ? src[(size_t)k * 128 + n] : 0.f;
    dst[(size_t)n * Kp + k] = f2bf(v);
  }
}

// ============ CSR build ============
struct EdgeCfg { const int* dst[NCLS]; int cnt[NCLS]; };

__global__ __launch_bounds__(256)
void hist_k(EdgeCfg cfg, int* __restrict__ ptrs)
{
  const int c = blockIdx.y;
  const int i = blockIdx.x * 256 + threadIdx.x;
  if (i < cfg.cnt[c]) atomicAdd(ptrs + (size_t)c * (N_NODES + 1) + cfg.dst[c][i], 1);
}

__global__ __launch_bounds__(256)
void scan1_k(const int* __restrict__ ptrs, int* __restrict__ part)
{
  const int c = blockIdx.y, b = blockIdx.x;
  const int* d = ptrs + (size_t)c * (N_NODES + 1) + b * 1024;
  const int rem = min(1024, N_NODES - b * 1024);
  int s = 0;
  for (int j = threadIdx.x; j < rem; j += 256) s += d[j];
  #pragma unroll
  for (int off = 32; off; off >>= 1) s += __shfl_xor(s, off, 64);
  __shared__ int r[4];
  if ((threadIdx.x & 63) == 0) r[threadIdx.x >> 6] = s;
  __syncthreads();
  if (threadIdx.x == 0) part[c * NCHUNK + b] = r[0] + r[1] + r[2] + r[3];
}

__global__ __launch_bounds__(64)
void scan2_k(int* __restrict__ part, int* __restrict__ ptrs)
{
  const int c = blockIdx.x;
  if (threadIdx.x) return;
  int* p = part + c * NCHUNK;
  int run = 0;
  for (int b = 0; b < NCHUNK; b++) { const int t = p[b]; p[b] = run; run += t; }
  ptrs[(size_t)c * (N_NODES + 1) + N_NODES] = run;
}

__global__ __launch_bounds__(256)
void scan3_k(int* __restrict__ ptrs, const int* __restrict__ part)
{
  const int c = blockIdx.y, b = blockIdx.x;
  int* d = ptrs + (size_t)c * (N_NODES + 1) + b * 1024;
  const int base = part[c * NCHUNK + b];
  const int gbase = b * 1024;
  const int i0 = threadIdx.x * 4;
  int v[4];
  #pragma unroll
  for (int j = 0; j < 4; j++) v[j] = (gbase + i0 + j < N_NODES) ? d[i0 + j] : 0;
  const int tsum = v[0] + v[1] + v[2] + v[3];
  __shared__ int sc[256];
  sc[threadIdx.x] = tsum;
  __syncthreads();
  #pragma unroll
  for (int off = 1; off < 256; off <<= 1) {
    const int t = (threadIdx.x >= off) ? sc[threadIdx.x - off] : 0;
    __syncthreads();
    sc[threadIdx.x] += t;
    __syncthreads();
  }
  int run = sc[threadIdx.x] - tsum + base;
  #pragma unroll
  for (int j = 0; j < 4; j++) {
    if (gbase + i0 + j < N_NODES) d[i0 + j] = run;
    run += v[j];
  }
}

__host__ __device__ constexpr int idx_base(int c) {
  return (c < 12) ? c * NEP : 12 * NEP + (c - 12) * NEL;
}

__global__ __launch_bounds__(256)
void fill_k(EdgeCfg cfg, int* __restrict__ ptrs, int* __restrict__ idxs)
{
  const int c = blockIdx.y;
  const int i = blockIdx.x * 256 + threadIdx.x;
  if (i >= cfg.cnt[c]) return;
  const int d = cfg.dst[c][i];
  const int slot = atomicAdd(ptrs + (size_t)c * (N_NODES + 1) + d, 1);
  idxs[idx_base(c) + slot] = i;
}

// ============ gather-reduce: T[d] += sum over msgs (bf16 arena) ============
__global__ __launch_bounds__(256)
void gather_k(const int* __restrict__ end, const int* __restrict__ idx,
              const u16* __restrict__ Msg, float* __restrict__ T)
{
  const int lane = threadIdx.x & 63;
  const int nw = gridDim.x * 4;
  for (int d = blockIdx.x * 4 + (threadIdx.x >> 6); d < N_NODES; d += nw) {
    const int hi = end[d];
    const int lo = d ? end[d - 1] : 0;
    if (lo == hi) continue;
    float ax = 0.f, ay = 0.f;
    for (int p = lo; p < hi; ++p) {
      const u32 m = *(const u32*)(Msg + (size_t)idx[p] * CDIM + lane * 2);
      ax += bflo(m); ay += bfhi(m);
    }
    float2* tp = (float2*)(T + (size_t)d * CDIM + lane * 2);
    float2 t = *tp; t.x += ax; t.y += ay; *tp = t;
  }
}

__global__ __launch_bounds__(256)
void gn_relu_k(float* __restrict__ T, const float* __restrict__ g,
               const float* __restrict__ b, int M)
{
  const int lane = threadIdx.x & 63;
  const int wid = blockIdx.x * 4 + (threadIdx.x >> 6);
  const int nw = gridDim.x * 4;
  const float2 g2 = *(const float2*)(g + lane * 2);
  const float2 b2 = *(const float2*)(b + lane * 2);
  for (int row = wid; row < M; row += nw) {
    float2 v = *(float2*)(T + (size_t)row * 128 + lane * 2);
    float s1 = v.x + v.y, s2 = v.x * v.x + v.y * v.y;
    #pragma unroll
    for (int off = 32; off; off >>= 1) {
      s1 += __shfl_xor(s1, off, 64);
      s2 += __shfl_xor(s2, off, 64);
    }
    const float mean = s1 * (1.0f / 128.0f);
    const float rstd = rsqrtf(s2 * (1.0f / 128.0f) - mean * mean + 1e-5f);
    v.x = fmaxf(0.f, (v.x - mean) * rstd * g2.x + b2.x);
    v.y = fmaxf(0.f, (v.y - mean) * rstd * g2.y + b2.y);
    *(float2*)(T + (size_t)row * 128 + lane * 2) = v;
  }
}

__global__ __launch_bounds__(256)
void copy_k(const float* __restrict__ src, float* __restrict__ dst, int n)
{
  const int i = blockIdx.x * 256 + threadIdx.x;
  if (i < n) dst[i] = src[i];
}

extern "C" void kernel_launch(void* const* d_in, const int* in_sizes, int n_in,
                              void* d_out, int out_size, void* d_ws, size_t ws_size,
                              hipStream_t stream) {
  const float* control   = (const float*)d_in[0];
  const float* turn      = (const float*)d_in[1];
  const float* intersect = (const float*)d_in[2];
  const float* ctrs      = (const float*)d_in[3];
  const float* feats     = (const float*)d_in[4];
  const int*   pre   = (const int*)d_in[5];
  const int*   suc   = (const int*)d_in[6];
  const int*   left  = (const int*)d_in[7];
  const int*   right = (const int*)d_in[8];
  const float* w_in1   = (const float*)d_in[9];
  const float* b_in1   = (const float*)d_in[10];
  const float* w_in2   = (const float*)d_in[11];
  const float* gn_in_g = (const float*)d_in[12];
  const float* gn_in_b = (const float*)d_in[13];
  const float* w_seg1   = (const float*)d_in[14];
  const float* b_seg1   = (const float*)d_in[15];
  const float* w_seg2   = (const float*)d_in[16];
  const float* gn_seg_g = (const float*)d_in[17];
  const float* gn_seg_b = (const float*)d_in[18];
  const float* w_meta    = (const float*)d_in[19];
  const float* gn_meta_g = (const float*)d_in[20];
  const float* gn_meta_b = (const float*)d_in[21];
  const float* ctr_w   = (const float*)d_in[22];
  const float* pre_w   = (const float*)d_in[23];
  const float* suc_w   = (const float*)d_in[24];
  const float* left_w  = (const float*)d_in[25];
  const float* right_w = (const float*)d_in[26];
  const float* norm_g  = (const float*)d_in[27];
  const float* norm_b  = (const float*)d_in[28];
  const float* ctr2_w  = (const float*)d_in[29];
  const float* ctr2_g  = (const float*)d_in[30];
  const float* ctr2_b  = (const float*)d_in[31];

  const size_t NF = (size_t)N_NODES * CDIM;
  char* w = (char*)d_ws;
  float* F  = (float*)w;  w += NF * 4;
  float* T  = (float*)w;  w += NF * 4;
  u16* Fb   = (u16*)w;    w += NF * 2;
  u16* Arena = (u16*)w;   w += (size_t)NEP * CDIM * 2;
  u16* Wt   = (u16*)w;    w += (size_t)(67 * 16384 + 128 * 160) * 2; // 66 sq + meta slack
  int* ptrs = (int*)w;    w += (size_t)NCLS * (N_NODES + 1) * 4;
  int* idxs = (int*)w;    w += (size_t)(12 * NEP + 2 * NEL) * 4;
  int* part = (int*)w;
  float* out = (float*)d_out;

  EdgeCfg cfg;
  const int* srcp[NCLS];
  for (int s = 0; s < NSCALE; s++) {
    cfg.dst[s] = pre + (size_t)s * 2 * NEP;       cfg.cnt[s] = NEP;
    srcp[s]    = pre + ((size_t)s * 2 + 1) * NEP;
    cfg.dst[6 + s] = suc + (size_t)s * 2 * NEP;   cfg.cnt[6 + s] = NEP;
    srcp[6 + s]    = suc + ((size_t)s * 2 + 1) * NEP;
  }
  cfg.dst[12] = left;  cfg.cnt[12] = NEL; srcp[12] = left + NEL;
  cfg.dst[13] = right; cfg.cnt[13] = NEL; srcp[13] = right + NEL;

  const dim3 blk(256);
  const dim3 gN((N_NODES + 127) / 128);   // 1563
  const dim3 gEP((NEP + 127) / 128);      // 782
  const dim3 gEL((NEL + 127) / 128);      // 196
  const dim3 gW(N_NODES / 64);            // 3125 (gather/gn wave-per-row grids)
  const dim3 gHist((NEP + 255) / 256, NCLS);
  const dim3 gScan(NCHUNK, NCLS);

  // ---- weight prep + CSR build ----
  prep_k<<<dim3(67), blk, 0, stream>>>(w_in2, w_seg2, ctr_w, ctr2_w, left_w, right_w,
                                       pre_w, suc_w, w_meta, Wt);
  (void)hipMemsetAsync(ptrs, 0, (size_t)NCLS * (N_NODES + 1) * sizeof(int), stream);
  hist_k<<<gHist, blk, 0, stream>>>(cfg, ptrs);
  scan1_k<<<gScan, blk, 0, stream>>>(ptrs, part);
  scan2_k<<<dim3(NCLS), dim3(64), 0, stream>>>(part, ptrs);
  scan3_k<<<gScan, blk, 0, stream>>>(ptrs, part);
  fill_k<<<gHist, blk, 0, stream>>>(cfg, ptrs, idxs);

  // ---- prologue: a-branch -> T, b-branch -> F, meta -> F (+Fb) ----
  mm_k<P_TWO, E_GN><<<gN, blk, 0, stream>>>(N_NODES, 128, 128, ctrs, nullptr, nullptr,
      w_in1, b_in1, nullptr, nullptr, Wt + 0 * 16384, T, nullptr, gn_in_g, gn_in_b, nullptr);
  mm_k<P_TWO, E_GN><<<gN, blk, 0, stream>>>(N_NODES, 128, 128, feats, nullptr, nullptr,
      w_seg1, b_seg1, nullptr, nullptr, Wt + 1 * 16384, F, nullptr, gn_seg_g, gn_seg_b, nullptr);
  mm_k<P_META, E_GN | E_RELU><<<gN, blk, 0, stream>>>(N_NODES, 132, 160, T, nullptr, F,
      turn, control, intersect, nullptr, Wt + 66 * 16384, F, Fb, gn_meta_g, gn_meta_b, nullptr);

  for (int i = 0; i < 4; i++) {
    // temp = feat @ ctr_w[i] -> T (fp32)
    mm_k<P_PLAIN, E_STORE><<<gN, blk, 0, stream>>>(N_NODES, 128, 128, nullptr, Fb, nullptr,
        nullptr, nullptr, nullptr, nullptr, Wt + (size_t)(2 + i) * 16384, T, nullptr, nullptr, nullptr, nullptr);
    // 14 edge classes: gathered msg GEMM -> bf16 arena, then CSR gather-reduce -> T
    for (int c = 0; c < NCLS; c++) {
      const u16* Wc =
          (c < 6)  ? Wt + (size_t)(18 + i * 6 + c) * 16384 :
          (c < 12) ? Wt + (size_t)(42 + i * 6 + (c - 6)) * 16384 :
          (c == 12) ? Wt + (size_t)(10 + i) * 16384 :
                      Wt + (size_t)(14 + i) * 16384;
      mm_k<P_GATHER, E_BF16><<<(c < 12) ? gEP : gEL, blk, 0, stream>>>(cfg.cnt[c], 128, 128,
          nullptr, Fb, nullptr, nullptr, nullptr, nullptr, srcp[c], Wc,
          nullptr, Arena, nullptr, nullptr, nullptr);
      gather_k<<<gW, blk, 0, stream>>>(ptrs + (size_t)c * (N_NODES + 1),
          idxs + idx_base(c), Arena, T);
    }
    // T = relu(GN(T))
    gn_relu_k<<<gW, blk, 0, stream>>>(T, norm_g + i * 128, norm_b + i * 128, N_NODES);
    // feat = relu(GN(T @ ctr2_w[i]) + res) -> F (+Fb), last layer -> out
    mm_k<P_CVT32, E_GN | E_RES | E_RELU><<<gN, blk, 0, stream>>>(N_NODES, 128, 128, T, nullptr,
        nullptr, nullptr, nullptr, nullptr, nullptr, Wt + (size_t)(6 + i) * 16384,
        (i == 3) ? out : F, (i == 3) ? nullptr : Fb, ctr2_g + i * 128, ctr2_b + i * 128, F);
  }

  copy_k<<<dim3((2 * N_NODES + 255) / 256), blk, 0, stream>>>(ctrs, out + NF, 2 * N_NODES);
}

// Round 5
// 2232.716 us; speedup vs baseline: 8.7592x; 1.9315x over previous
//
#include <hip/hip_runtime.h>

#define N_NODES 200000
#define CDIM 128
#define NSCALE 6
#define NEP 100000
#define NEL 25000
#define NCLS 14
#define NCHUNK 196   // ceil(200000/1024)

typedef unsigned short u16;
typedef unsigned int u32;

using fragAB = __attribute__((ext_vector_type(8))) short;  // 8 bf16
using fragC  = __attribute__((ext_vector_type(4))) float;  // 4 fp32

enum { P_PLAIN = 0, P_TWO = 1, P_META = 2 };
enum { E_GN = 1, E_RELU = 2 };

__device__ __forceinline__ float4 ld4(const float* p) { return *(const float4*)p; }

__device__ __forceinline__ u16 f2bf(float f) {
  u32 u = __builtin_bit_cast(u32, f);
  u = (u + 0x7fff + ((u >> 16) & 1)) >> 16;
  return (u16)u;
}
__device__ __forceinline__ u32 pk2(float a, float b) {
  return (u32)f2bf(a) | ((u32)f2bf(b) << 16);
}
__device__ __forceinline__ float bflo(u32 u) { return __builtin_bit_cast(float, u << 16); }
__device__ __forceinline__ float bfhi(u32 u) { return __builtin_bit_cast(float, u & 0xffff0000u); }

__device__ __forceinline__ void acc16(float* s, uint4 a, uint4 b) {
  s[0] += bflo(a.x); s[1] += bfhi(a.x); s[2]  += bflo(a.y); s[3]  += bfhi(a.y);
  s[4] += bflo(a.z); s[5] += bfhi(a.z); s[6]  += bflo(a.w); s[7]  += bfhi(a.w);
  s[8] += bflo(b.x); s[9] += bfhi(b.x); s[10] += bflo(b.y); s[11] += bfhi(b.y);
  s[12] += bflo(b.z); s[13] += bfhi(b.z); s[14] += bflo(b.w); s[15] += bfhi(b.w);
}

__host__ __device__ constexpr int idx_base(int c) {
  return (c < 12) ? c * NEP : 12 * NEP + (c - 12) * NEL;
}

// weight slot table (prep_k layout): 0 in2, 1 seg2, 2-5 ctr, 6-9 ctr2, 10-13 left,
// 14-17 right, 18-41 pre[i*6+s], 42-65 suc[i*6+s], 66 meta
__device__ __forceinline__ int wslot(int li, int c) {
  if (c < 0)  return 2 + li;
  if (c < 6)  return 18 + li * 6 + c;
  if (c < 12) return 42 + li * 6 + (c - 6);
  return (c == 12) ? (10 + li) : (14 + li);
}

// ================= prologue MFMA GEMM (a/b/meta branches) =================
// Block 256 = 4 waves (2x2), tile 128x128, BK=32. Wt bf16 transposed [128][Kp].
template<int PRO, int EPI>
__global__ __launch_bounds__(256)
void mm_k(int M, int Kp,
          const float* __restrict__ Af, const float* __restrict__ A2f,
          const float* __restrict__ e0, const float* __restrict__ e1, const float* __restrict__ e2,
          const u16* __restrict__ Wt,
          float* __restrict__ Y, u16* __restrict__ Yb,
          const float* __restrict__ gn_g, const float* __restrict__ gn_b)
{
  constexpr int LSTR = 56;
  __shared__ u16 As[128 * LSTR];
  __shared__ u16 Bs[128 * LSTR];

  const int tid = threadIdx.x;
  const int lane = tid & 63, wid = tid >> 6;
  const int wm = (wid >> 1) * 64, wn = (wid & 1) * 64;
  const int q = lane >> 4, l16 = lane & 15;
  const int row0 = blockIdx.x * 128;
  const int srow = tid >> 1, shalf = tid & 1;

  fragC acc[4][4];
  #pragma unroll
  for (int i = 0; i < 4; i++)
    #pragma unroll
    for (int j = 0; j < 4; j++)
      #pragma unroll
      for (int e = 0; e < 4; e++) acc[i][j][e] = 0.0f;

  const int sgrow = row0 + srow;
  const bool svalid = (sgrow < M);
  float x0 = 0.f, x1 = 0.f, mx = 0.f, my = 0.f, mc = 0.f, mi = 0.f;
  if constexpr (PRO == P_TWO) {
    if (svalid) { x0 = Af[(size_t)sgrow * 2]; x1 = Af[(size_t)sgrow * 2 + 1]; }
  }
  if constexpr (PRO == P_META) {
    if (svalid) { mx = e0[(size_t)sgrow * 2]; my = e0[(size_t)sgrow * 2 + 1]; mc = e1[sgrow]; mi = e2[sgrow]; }
  }

  const int nk = Kp >> 5;
  for (int kt = 0; kt < nk; ++kt) {
    const int k0 = kt * 32 + shalf * 16;
    {
      u16* adst = &As[srow * LSTR + shalf * 16];
      float v[16];
      #pragma unroll
      for (int j = 0; j < 16; j++) v[j] = 0.f;
      if constexpr (PRO == P_TWO) {
        #pragma unroll
        for (int j0 = 0; j0 < 16; j0 += 4) {
          float4 wa = ld4(e0 + k0 + j0);
          float4 wb = ld4(e0 + 128 + k0 + j0);
          float4 bb = ld4(e1 + k0 + j0);
          v[j0]     = fmaxf(0.f, fmaf(x0, wa.x, fmaf(x1, wb.x, bb.x)));
          v[j0 + 1] = fmaxf(0.f, fmaf(x0, wa.y, fmaf(x1, wb.y, bb.y)));
          v[j0 + 2] = fmaxf(0.f, fmaf(x0, wa.z, fmaf(x1, wb.z, bb.z)));
          v[j0 + 3] = fmaxf(0.f, fmaf(x0, wa.w, fmaf(x1, wb.w, bb.w)));
        }
      } else { // P_META
        if (svalid) {
          if (k0 < 128) {
            const float* sa = Af + (size_t)sgrow * 128 + k0;
            const float* sb = A2f + (size_t)sgrow * 128 + k0;
            #pragma unroll
            for (int j0 = 0; j0 < 16; j0 += 4) {
              float4 a = ld4(sa + j0), b = ld4(sb + j0);
              v[j0]     = fmaxf(0.f, a.x + b.x);
              v[j0 + 1] = fmaxf(0.f, a.y + b.y);
              v[j0 + 2] = fmaxf(0.f, a.z + b.z);
              v[j0 + 3] = fmaxf(0.f, a.w + b.w);
            }
          } else {
            #pragma unroll
            for (int j = 0; j < 16; j++) {
              const int kk = k0 + j - 128;
              v[j] = (kk == 0) ? mx : (kk == 1) ? my : (kk == 2) ? mc : (kk == 3) ? mi : 0.f;
            }
          }
        }
      }
      u32 p[8];
      #pragma unroll
      for (int j = 0; j < 8; j++) p[j] = pk2(v[2 * j], v[2 * j + 1]);
      *(uint4*)adst = make_uint4(p[0], p[1], p[2], p[3]);
      *(uint4*)(adst + 8) = make_uint4(p[4], p[5], p[6], p[7]);
    }
    {
      const u16* s = Wt + (size_t)srow * Kp + k0;
      uint4 b0 = *(const uint4*)s, b1 = *(const uint4*)(s + 8);
      u16* bdst = &Bs[srow * LSTR + shalf * 16];
      *(uint4*)bdst = b0; *(uint4*)(bdst + 8) = b1;
    }
    __syncthreads();
    fragAB af[4], bf[4];
    #pragma unroll
    for (int t = 0; t < 4; t++) af[t] = *(const fragAB*)&As[(wm + t * 16 + l16) * LSTR + q * 8];
    #pragma unroll
    for (int t = 0; t < 4; t++) bf[t] = *(const fragAB*)&Bs[(wn + t * 16 + l16) * LSTR + q * 8];
    #pragma unroll
    for (int mt = 0; mt < 4; mt++)
      #pragma unroll
      for (int nt = 0; nt < 4; nt++)
        acc[mt][nt] = __builtin_amdgcn_mfma_f32_16x16x32_bf16(af[mt], bf[nt], acc[mt][nt], 0, 0, 0);
    __syncthreads();
  }

  // GN epilogue
  __shared__ float2 red[128][2];
  __shared__ float2 stats[128];
  #pragma unroll
  for (int mt = 0; mt < 4; mt++)
    #pragma unroll
    for (int r = 0; r < 4; r++) {
      float s1 = acc[mt][0][r] + acc[mt][1][r] + acc[mt][2][r] + acc[mt][3][r];
      float s2 = acc[mt][0][r] * acc[mt][0][r] + acc[mt][1][r] * acc[mt][1][r]
               + acc[mt][2][r] * acc[mt][2][r] + acc[mt][3][r] * acc[mt][3][r];
      #pragma unroll
      for (int off = 1; off < 16; off <<= 1) {
        s1 += __shfl_xor(s1, off, 64);
        s2 += __shfl_xor(s2, off, 64);
      }
      if (l16 == 0) red[wm + mt * 16 + q * 4 + r][wid & 1] = make_float2(s1, s2);
    }
  __syncthreads();
  if (tid < 128) {
    const float2 p0 = red[tid][0], p1 = red[tid][1];
    const float m = (p0.x + p1.x) * (1.0f / 128.0f);
    const float var = (p0.y + p1.y) * (1.0f / 128.0f) - m * m;
    stats[tid] = make_float2(m, rsqrtf(var + 1e-5f));
  }
  __syncthreads();
  float gl[4], bl[4];
  #pragma unroll
  for (int nt = 0; nt < 4; nt++) {
    gl[nt] = gn_g[wn + nt * 16 + l16];
    bl[nt] = gn_b[wn + nt * 16 + l16];
  }
  #pragma unroll
  for (int mt = 0; mt < 4; mt++)
    #pragma unroll
    for (int r = 0; r < 4; r++) {
      const int rl = wm + mt * 16 + q * 4 + r;
      const int grow = row0 + rl;
      if (grow >= M) continue;
      const float2 st = stats[rl];
      #pragma unroll
      for (int nt = 0; nt < 4; nt++) {
        const int col = wn + nt * 16 + l16;
        float v = (acc[mt][nt][r] - st.x) * st.y * gl[nt] + bl[nt];
        if constexpr ((EPI & E_RELU) != 0) v = fmaxf(v, 0.f);
        if (Y)  Y[(size_t)grow * 128 + col] = v;
        if (Yb) Yb[(size_t)grow * 128 + col] = f2bf(v);
      }
    }
}

// ================= fused per-layer kernel =================
// acc1 = Fb@ctr + sum_c CSR_agg_c(Fb)@W_c ; feat_mid = relu(GN1(acc1)) -> LDS
// acc2 = feat_mid@ctr2 ; out = relu(GN2(acc2) + res_bf16)
__global__ __launch_bounds__(256, 3)
void layer_k(const u16* __restrict__ Fin, u16* __restrict__ Fout,
             float* __restrict__ outf,
             const int* __restrict__ ptrs, const int* __restrict__ idxs,
             const u16* __restrict__ Wt, int li,
             const float* __restrict__ g1, const float* __restrict__ b1,
             const float* __restrict__ g2, const float* __restrict__ b2)
{
  constexpr int LSTR = 56, FSTR = 136;
  __shared__ u16 ldsA[128 * FSTR];   // GEMM1 A-tile (stride 56, first 14336 B) / feat_mid (stride 136)
  __shared__ u16 Bs[128 * LSTR];
  __shared__ float2 red[128][2];
  __shared__ float2 stats[128];

  const int tid = threadIdx.x;
  const int lane = tid & 63, wid = tid >> 6;
  const int wm = (wid >> 1) * 64, wn = (wid & 1) * 64;
  const int q = lane >> 4, l16 = lane & 15;
  const int row0 = blockIdx.x * 128;
  const int srow = tid >> 1, shalf = tid & 1;
  const int sgrow = row0 + srow;
  const bool svalid = (sgrow < N_NODES);

  fragC acc[4][4];
  #pragma unroll
  for (int i = 0; i < 4; i++)
    #pragma unroll
    for (int j = 0; j < 4; j++)
      #pragma unroll
      for (int e = 0; e < 4; e++) acc[i][j][e] = 0.0f;

  // ---------- GEMM1: ctr (c=-1) + 14 aggregated classes ----------
  for (int c = -1; c < NCLS; ++c) {
    const u16* W = Wt + (size_t)wslot(li, c) * 16384;
    int lo = 0, hi = 0;
    const int* ic = nullptr;
    if (c >= 0) {
      const int* pc = ptrs + (size_t)c * (N_NODES + 1);
      if (svalid) { hi = pc[sgrow]; lo = sgrow ? pc[sgrow - 1] : 0; }
      ic = idxs + idx_base(c);
    }
    #pragma unroll
    for (int kt = 0; kt < 4; ++kt) {
      const int k0 = kt * 32 + shalf * 16;
      // A stage
      u16* adst = &ldsA[srow * LSTR + shalf * 16];
      if (c < 0) {
        uint4 a = make_uint4(0, 0, 0, 0), b = a;
        if (svalid) {
          const u16* s = Fin + (size_t)sgrow * 128 + k0;
          a = *(const uint4*)s; b = *(const uint4*)(s + 8);
        }
        *(uint4*)adst = a; *(uint4*)(adst + 8) = b;
      } else {
        float s[16];
        #pragma unroll
        for (int j = 0; j < 16; j++) s[j] = 0.f;
        for (int p = lo; p < hi; ++p) {
          const u16* sp = Fin + (size_t)ic[p] * 128 + k0;
          acc16(s, *(const uint4*)sp, *(const uint4*)(sp + 8));
        }
        u32 pk[8];
        #pragma unroll
        for (int j = 0; j < 8; j++) pk[j] = pk2(s[2 * j], s[2 * j + 1]);
        *(uint4*)adst = make_uint4(pk[0], pk[1], pk[2], pk[3]);
        *(uint4*)(adst + 8) = make_uint4(pk[4], pk[5], pk[6], pk[7]);
      }
      // B stage
      {
        const u16* ws = W + (size_t)srow * 128 + k0;
        uint4 a = *(const uint4*)ws, b = *(const uint4*)(ws + 8);
        u16* bdst = &Bs[srow * LSTR + shalf * 16];
        *(uint4*)bdst = a; *(uint4*)(bdst + 8) = b;
      }
      __syncthreads();
      fragAB af[4], bf[4];
      #pragma unroll
      for (int t = 0; t < 4; t++) af[t] = *(const fragAB*)&ldsA[(wm + t * 16 + l16) * LSTR + q * 8];
      #pragma unroll
      for (int t = 0; t < 4; t++) bf[t] = *(const fragAB*)&Bs[(wn + t * 16 + l16) * LSTR + q * 8];
      #pragma unroll
      for (int mt = 0; mt < 4; mt++)
        #pragma unroll
        for (int nt = 0; nt < 4; nt++)
          acc[mt][nt] = __builtin_amdgcn_mfma_f32_16x16x32_bf16(af[mt], bf[nt], acc[mt][nt], 0, 0, 0);
      __syncthreads();
    }
  }

  // ---------- GN1 + relu -> feat_mid in LDS (stride FSTR) ----------
  #pragma unroll
  for (int mt = 0; mt < 4; mt++)
    #pragma unroll
    for (int r = 0; r < 4; r++) {
      float s1 = acc[mt][0][r] + acc[mt][1][r] + acc[mt][2][r] + acc[mt][3][r];
      float s2 = acc[mt][0][r] * acc[mt][0][r] + acc[mt][1][r] * acc[mt][1][r]
               + acc[mt][2][r] * acc[mt][2][r] + acc[mt][3][r] * acc[mt][3][r];
      #pragma unroll
      for (int off = 1; off < 16; off <<= 1) {
        s1 += __shfl_xor(s1, off, 64);
        s2 += __shfl_xor(s2, off, 64);
      }
      if (l16 == 0) red[wm + mt * 16 + q * 4 + r][wid & 1] = make_float2(s1, s2);
    }
  __syncthreads();
  if (tid < 128) {
    const float2 p0 = red[tid][0], p1 = red[tid][1];
    const float m = (p0.x + p1.x) * (1.0f / 128.0f);
    const float var = (p0.y + p1.y) * (1.0f / 128.0f) - m * m;
    stats[tid] = make_float2(m, rsqrtf(var + 1e-5f));
  }
  __syncthreads();
  {
    float gl[4], bl[4];
    #pragma unroll
    for (int nt = 0; nt < 4; nt++) {
      gl[nt] = g1[wn + nt * 16 + l16];
      bl[nt] = b1[wn + nt * 16 + l16];
    }
    #pragma unroll
    for (int mt = 0; mt < 4; mt++)
      #pragma unroll
      for (int r = 0; r < 4; r++) {
        const int rl = wm + mt * 16 + q * 4 + r;
        const float2 st = stats[rl];
        #pragma unroll
        for (int nt = 0; nt < 4; nt++) {
          const int col = wn + nt * 16 + l16;
          const float v = fmaxf(0.f, (acc[mt][nt][r] - st.x) * st.y * gl[nt] + bl[nt]);
          ldsA[rl * FSTR + col] = f2bf(v);
        }
      }
  }

  // ---------- GEMM2: feat_mid @ ctr2 ----------
  #pragma unroll
  for (int i = 0; i < 4; i++)
    #pragma unroll
    for (int j = 0; j < 4; j++)
      #pragma unroll
      for (int e = 0; e < 4; e++) acc[i][j][e] = 0.0f;
  {
    const u16* W2 = Wt + (size_t)(6 + li) * 16384;
    #pragma unroll
    for (int kt = 0; kt < 4; ++kt) {
      const int k0 = kt * 32 + shalf * 16;
      const u16* ws = W2 + (size_t)srow * 128 + k0;
      uint4 a = *(const uint4*)ws, b = *(const uint4*)(ws + 8);
      u16* bdst = &Bs[srow * LSTR + shalf * 16];
      *(uint4*)bdst = a; *(uint4*)(bdst + 8) = b;
      __syncthreads();
      fragAB af[4], bf[4];
      #pragma unroll
      for (int t = 0; t < 4; t++) af[t] = *(const fragAB*)&ldsA[(wm + t * 16 + l16) * FSTR + kt * 32 + q * 8];
      #pragma unroll
      for (int t = 0; t < 4; t++) bf[t] = *(const fragAB*)&Bs[(wn + t * 16 + l16) * LSTR + q * 8];
      #pragma unroll
      for (int mt = 0; mt < 4; mt++)
        #pragma unroll
        for (int nt = 0; nt < 4; nt++)
          acc[mt][nt] = __builtin_amdgcn_mfma_f32_16x16x32_bf16(af[mt], bf[nt], acc[mt][nt], 0, 0, 0);
      __syncthreads();
    }
  }

  // ---------- GN2 + residual(bf16) + relu + store ----------
  #pragma unroll
  for (int mt = 0; mt < 4; mt++)
    #pragma unroll
    for (int r = 0; r < 4; r++) {
      float s1 = acc[mt][0][r] + acc[mt][1][r] + acc[mt][2][r] + acc[mt][3][r];
      float s2 = acc[mt][0][r] * acc[mt][0][r] + acc[mt][1][r] * acc[mt][1][r]
               + acc[mt][2][r] * acc[mt][2][r] + acc[mt][3][r] * acc[mt][3][r];
      #pragma unroll
      for (int off = 1; off < 16; off <<= 1) {
        s1 += __shfl_xor(s1, off, 64);
        s2 += __shfl_xor(s2, off, 64);
      }
      if (l16 == 0) red[wm + mt * 16 + q * 4 + r][wid & 1] = make_float2(s1, s2);
    }
  __syncthreads();
  if (tid < 128) {
    const float2 p0 = red[tid][0], p1 = red[tid][1];
    const float m = (p0.x + p1.x) * (1.0f / 128.0f);
    const float var = (p0.y + p1.y) * (1.0f / 128.0f) - m * m;
    stats[tid] = make_float2(m, rsqrtf(var + 1e-5f));
  }
  __syncthreads();
  {
    float gl[4], bl[4];
    #pragma unroll
    for (int nt = 0; nt < 4; nt++) {
      gl[nt] = g2[wn + nt * 16 + l16];
      bl[nt] = b2[wn + nt * 16 + l16];
    }
    #pragma unroll
    for (int mt = 0; mt < 4; mt++)
      #pragma unroll
      for (int r = 0; r < 4; r++) {
        const int rl = wm + mt * 16 + q * 4 + r;
        const int grow = row0 + rl;
        if (grow >= N_NODES) continue;
        const float2 st = stats[rl];
        #pragma unroll
        for (int nt = 0; nt < 4; nt++) {
          const int col = wn + nt * 16 + l16;
          const float res = bflo((u32)Fin[(size_t)grow * 128 + col]);
          float v = (acc[mt][nt][r] - st.x) * st.y * gl[nt] + bl[nt] + res;
          v = fmaxf(v, 0.f);
          if (outf) outf[(size_t)grow * 128 + col] = v;
          else      Fout[(size_t)grow * 128 + col] = f2bf(v);
        }
      }
  }
}

// ============ weight prep: fp32 [K,128] -> bf16 transposed [128,Kp] ============
__global__ __launch_bounds__(256)
void prep_k(const float* __restrict__ in2, const float* __restrict__ seg2,
            const float* __restrict__ ctr, const float* __restrict__ ctr2,
            const float* __restrict__ lw, const float* __restrict__ rw,
            const float* __restrict__ pw, const float* __restrict__ sw,
            const float* __restrict__ meta, u16* __restrict__ Wt)
{
  const int id = blockIdx.x;
  const float* src;
  int K = 128, Kp = 128;
  if (id == 0) src = in2;
  else if (id == 1) src = seg2;
  else if (id < 6)  src = ctr  + (size_t)(id - 2) * 16384;
  else if (id < 10) src = ctr2 + (size_t)(id - 6) * 16384;
  else if (id < 14) src = lw   + (size_t)(id - 10) * 16384;
  else if (id < 18) src = rw   + (size_t)(id - 14) * 16384;
  else if (id < 42) src = pw   + (size_t)(id - 18) * 16384;
  else if (id < 66) src = sw   + (size_t)(id - 42) * 16384;
  else { src = meta; K = 132; Kp = 160; }
  u16* dst = Wt + (size_t)id * 16384;
  const int tot = 128 * Kp;
  for (int e = threadIdx.x; e < tot; e += 256) {
    const int n = e & 127, k = e >> 7;
    const float v = (k < K) ? src[(size_t)k * 128 + n] : 0.f;
    dst[(size_t)n * Kp + k] = f2bf(v);
  }
}

// ============ CSR build ============
struct EdgeCfg { const int* dst[NCLS]; const int* src[NCLS]; int cnt[NCLS]; };

__global__ __launch_bounds__(256)
void hist_k(EdgeCfg cfg, int* __restrict__ ptrs)
{
  const int c = blockIdx.y;
  const int i = blockIdx.x * 256 + threadIdx.x;
  if (i < cfg.cnt[c]) atomicAdd(ptrs + (size_t)c * (N_NODES + 1) + cfg.dst[c][i], 1);
}

__global__ __launch_bounds__(256)
void scan1_k(const int* __restrict__ ptrs, int* __restrict__ part)
{
  const int c = blockIdx.y, b = blockIdx.x;
  const int* d = ptrs + (size_t)c * (N_NODES + 1) + b * 1024;
  const int rem = min(1024, N_NODES - b * 1024);
  int s = 0;
  for (int j = threadIdx.x; j < rem; j += 256) s += d[j];
  #pragma unroll
  for (int off = 32; off; off >>= 1) s += __shfl_xor(s, off, 64);
  __shared__ int r[4];
  if ((threadIdx.x & 63) == 0) r[threadIdx.x >> 6] = s;
  __syncthreads();
  if (threadIdx.x == 0) part[c * NCHUNK + b] = r[0] + r[1] + r[2] + r[3];
}

__global__ __launch_bounds__(64)
void scan2_k(int* __restrict__ part, int* __restrict__ ptrs)
{
  const int c = blockIdx.x;
  if (threadIdx.x) return;
  int* p = part + c * NCHUNK;
  int run = 0;
  for (int b = 0; b < NCHUNK; b++) { const int t = p[b]; p[b] = run; run += t; }
  ptrs[(size_t)c * (N_NODES + 1) + N_NODES] = run;
}

__global__ __launch_bounds__(256)
void scan3_k(int* __restrict__ ptrs, const int* __restrict__ part)
{
  const int c = blockIdx.y, b = blockIdx.x;
  int* d = ptrs + (size_t)c * (N_NODES + 1) + b * 1024;
  const int base = part[c * NCHUNK + b];
  const int gbase = b * 1024;
  const int i0 = threadIdx.x * 4;
  int v[4];
  #pragma unroll
  for (int j = 0; j < 4; j++) v[j] = (gbase + i0 + j < N_NODES) ? d[i0 + j] : 0;
  const int tsum = v[0] + v[1] + v[2] + v[3];
  __shared__ int sc[256];
  sc[threadIdx.x] = tsum;
  __syncthreads();
  #pragma unroll
  for (int off = 1; off < 256; off <<= 1) {
    const int t = (threadIdx.x >= off) ? sc[threadIdx.x - off] : 0;
    __syncthreads();
    sc[threadIdx.x] += t;
    __syncthreads();
  }
  int run = sc[threadIdx.x] - tsum + base;
  #pragma unroll
  for (int j = 0; j < 4; j++) {
    if (gbase + i0 + j < N_NODES) d[i0 + j] = run;
    run += v[j];
  }
}

// fill stores SOURCE node ids; ptrs become end-offsets
__global__ __launch_bounds__(256)
void fill_k(EdgeCfg cfg, int* __restrict__ ptrs, int* __restrict__ idxs)
{
  const int c = blockIdx.y;
  const int i = blockIdx.x * 256 + threadIdx.x;
  if (i >= cfg.cnt[c]) return;
  const int d = cfg.dst[c][i];
  const int slot = atomicAdd(ptrs + (size_t)c * (N_NODES + 1) + d, 1);
  idxs[idx_base(c) + slot] = cfg.src[c][i];
}

__global__ __launch_bounds__(256)
void copy_k(const float* __restrict__ src, float* __restrict__ dst, int n)
{
  const int i = blockIdx.x * 256 + threadIdx.x;
  if (i < n) dst[i] = src[i];
}

extern "C" void kernel_launch(void* const* d_in, const int* in_sizes, int n_in,
                              void* d_out, int out_size, void* d_ws, size_t ws_size,
                              hipStream_t stream) {
  const float* control   = (const float*)d_in[0];
  const float* turn      = (const float*)d_in[1];
  const float* intersect = (const float*)d_in[2];
  const float* ctrs      = (const float*)d_in[3];
  const float* feats     = (const float*)d_in[4];
  const int*   pre   = (const int*)d_in[5];
  const int*   suc   = (const int*)d_in[6];
  const int*   left  = (const int*)d_in[7];
  const int*   right = (const int*)d_in[8];
  const float* w_in1   = (const float*)d_in[9];
  const float* b_in1   = (const float*)d_in[10];
  const float* w_in2   = (const float*)d_in[11];
  const float* gn_in_g = (const float*)d_in[12];
  const float* gn_in_b = (const float*)d_in[13];
  const float* w_seg1   = (const float*)d_in[14];
  const float* b_seg1   = (const float*)d_in[15];
  const float* w_seg2   = (const float*)d_in[16];
  const float* gn_seg_g = (const float*)d_in[17];
  const float* gn_seg_b = (const float*)d_in[18];
  const float* w_meta    = (const float*)d_in[19];
  const float* gn_meta_g = (const float*)d_in[20];
  const float* gn_meta_b = (const float*)d_in[21];
  const float* ctr_w   = (const float*)d_in[22];
  const float* pre_w   = (const float*)d_in[23];
  const float* suc_w   = (const float*)d_in[24];
  const float* left_w  = (const float*)d_in[25];
  const float* right_w = (const float*)d_in[26];
  const float* norm_g  = (const float*)d_in[27];
  const float* norm_b  = (const float*)d_in[28];
  const float* ctr2_w  = (const float*)d_in[29];
  const float* ctr2_g  = (const float*)d_in[30];
  const float* ctr2_b  = (const float*)d_in[31];

  const size_t NF = (size_t)N_NODES * CDIM;
  char* w = (char*)d_ws;
  float* Ta = (float*)w;  w += NF * 4;           // a-branch
  float* Tb = (float*)w;  w += NF * 4;           // b-branch
  u16* Fb0  = (u16*)w;    w += NF * 2;
  u16* Fb1  = (u16*)w;    w += NF * 2;
  u16* Wt   = (u16*)w;    w += (size_t)(67 * 16384 + 128 * 160) * 2;
  int* ptrs = (int*)w;    w += (size_t)NCLS * (N_NODES + 1) * 4;
  int* idxs = (int*)w;    w += (size_t)(12 * NEP + 2 * NEL) * 4;
  int* part = (int*)w;
  float* out = (float*)d_out;

  EdgeCfg cfg;
  for (int s = 0; s < NSCALE; s++) {
    cfg.dst[s] = pre + (size_t)s * 2 * NEP;     cfg.src[s] = pre + ((size_t)s * 2 + 1) * NEP;     cfg.cnt[s] = NEP;
    cfg.dst[6 + s] = suc + (size_t)s * 2 * NEP; cfg.src[6 + s] = suc + ((size_t)s * 2 + 1) * NEP; cfg.cnt[6 + s] = NEP;
  }
  cfg.dst[12] = left;  cfg.src[12] = left + NEL;  cfg.cnt[12] = NEL;
  cfg.dst[13] = right; cfg.src[13] = right + NEL; cfg.cnt[13] = NEL;

  const dim3 blk(256);
  const dim3 gN((N_NODES + 127) / 128);   // 1563
  const dim3 gHist((NEP + 255) / 256, NCLS);
  const dim3 gScan(NCHUNK, NCLS);

  // ---- weight prep + CSR build ----
  prep_k<<<dim3(67), blk, 0, stream>>>(w_in2, w_seg2, ctr_w, ctr2_w, left_w, right_w,
                                       pre_w, suc_w, w_meta, Wt);
  (void)hipMemsetAsync(ptrs, 0, (size_t)NCLS * (N_NODES + 1) * sizeof(int), stream);
  hist_k<<<gHist, blk, 0, stream>>>(cfg, ptrs);
  scan1_k<<<gScan, blk, 0, stream>>>(ptrs, part);
  scan2_k<<<dim3(NCLS), dim3(64), 0, stream>>>(part, ptrs);
  scan3_k<<<gScan, blk, 0, stream>>>(ptrs, part);
  fill_k<<<gHist, blk, 0, stream>>>(cfg, ptrs, idxs);

  // ---- prologue: a-branch -> Ta, b-branch -> Tb, meta -> Fb0 (bf16 only) ----
  mm_k<P_TWO, E_GN><<<gN, blk, 0, stream>>>(N_NODES, 128, ctrs, nullptr,
      w_in1, b_in1, nullptr, Wt + 0 * 16384, Ta, nullptr, gn_in_g, gn_in_b);
  mm_k<P_TWO, E_GN><<<gN, blk, 0, stream>>>(N_NODES, 128, feats, nullptr,
      w_seg1, b_seg1, nullptr, Wt + 1 * 16384, Tb, nullptr, gn_seg_g, gn_seg_b);
  mm_k<P_META, E_GN | E_RELU><<<gN, blk, 0, stream>>>(N_NODES, 160, Ta, Tb,
      turn, control, intersect, Wt + 66 * 16384, nullptr, Fb0, gn_meta_g, gn_meta_b);

  // ---- 4 fused layers (double-buffered bf16 features) ----
  for (int i = 0; i < 4; i++) {
    const u16* Fin = (i & 1) ? Fb1 : Fb0;
    u16* Fout      = (i & 1) ? Fb0 : Fb1;
    layer_k<<<gN, blk, 0, stream>>>(Fin, Fout, (i == 3) ? out : nullptr,
        ptrs, idxs, Wt, i,
        norm_g + i * 128, norm_b + i * 128, ctr2_g + i * 128, ctr2_b + i * 128);
  }

  copy_k<<<dim3((2 * N_NODES + 255) / 256), blk, 0, stream>>>(ctrs, out + NF, 2 * N_NODES);
}